// Round 1
// baseline (163.382 us; speedup 1.0000x reference)
//
#include <hip/hip_runtime.h>
#include <hip/hip_bf16.h>
#include <stdint.h>

#define T_TOK 8192
#define DIN   1024
#define DOUT  1024
#define NEXP  8
#define CAP   1024           // T_TOK / NEXP
#define LN_EPS 1e-5f

#define BM 128
#define BN 128
#define BK 32
#define LDSS 48              // LDS leading-dim stride in bf16 elements (16B aligned rows)

typedef __attribute__((ext_vector_type(8))) short short8;
typedef __attribute__((ext_vector_type(4))) float f32x4;

__device__ __forceinline__ unsigned short f2bf(float f) {
    union { float f; unsigned int u; } v; v.f = f;
    unsigned int u = v.u;
    unsigned int r = u + 0x7FFFu + ((u >> 16) & 1u);   // round-to-nearest-even
    return (unsigned short)(r >> 16);
}

// ---- Kernel 1: W [E][K][N] fp32 -> Wt [E][N][K] bf16 (transpose + downcast) ----
__global__ __launch_bounds__(256) void wt_kernel(const float* __restrict__ W,
                                                 unsigned short* __restrict__ Wt) {
    __shared__ float tile[32][33];
    int e  = blockIdx.z;
    int k0 = blockIdx.y * 32;
    int n0 = blockIdx.x * 32;
    const float* Wp = W + (size_t)e * DIN * DOUT;
    unsigned short* Wtp = Wt + (size_t)e * DIN * DOUT;
    int tx = threadIdx.x;       // 0..31
    int ty = threadIdx.y;       // 0..7
#pragma unroll
    for (int r = 0; r < 4; r++)
        tile[ty + r * 8][tx] = Wp[(size_t)(k0 + ty + r * 8) * DOUT + (n0 + tx)];
    __syncthreads();
#pragma unroll
    for (int r = 0; r < 4; r++)
        Wtp[(size_t)(n0 + ty + r * 8) * DIN + (k0 + tx)] = f2bf(tile[tx][ty + r * 8]);
}

// ---- Kernel 2: grouped GEMM, h = relu(X_e * W_e + b_e) -> d_out (fp32) ----
// 128x128 tile, 4 waves, each wave 64x64 = 4x4 tiles of mfma_f32_16x16x32_bf16.
__global__ __launch_bounds__(256, 2) void gemm_kernel(
    const float* __restrict__ X,            // [T_TOK][DIN] fp32
    const unsigned short* __restrict__ Wt,  // [E][N][K] bf16
    const float* __restrict__ Bias,         // [E][DOUT] fp32
    float* __restrict__ H)                  // [T_TOK][DOUT] fp32
{
    __shared__ unsigned short As[BM * LDSS];
    __shared__ unsigned short Bs[BN * LDSS];

    int blk = blockIdx.x;           // 0..511
    int e   = blk >> 6;
    int tt  = blk & 63;
    int m0  = (tt >> 3) * BM;       // row offset within expert
    int n0  = (tt & 7) * BN;        // col offset within expert

    int tid  = threadIdx.x;
    int wave = tid >> 6;
    int lane = tid & 63;
    int wm   = (wave >> 1) * 64;
    int wn   = (wave & 1) * 64;
    int lrow = lane & 15;
    int quad = lane >> 4;

    const float* Xe = X + (size_t)(e * CAP + m0) * DIN;
    const unsigned short* We = Wt + (size_t)e * DOUT * DIN + (size_t)n0 * DIN;

    f32x4 acc[4][4];
#pragma unroll
    for (int i = 0; i < 4; i++)
#pragma unroll
        for (int j = 0; j < 4; j++)
            acc[i][j] = (f32x4)(0.0f);

    for (int k0 = 0; k0 < DIN; k0 += BK) {
        // Stage A: 128x32 fp32 -> bf16 LDS [M][K]
#pragma unroll
        for (int i = 0; i < 4; i++) {
            int idx = tid + i * 256;        // 0..1023
            int row = idx >> 3;             // 8 float4 per row
            int c4  = idx & 7;
            const float4 xv = *(const float4*)(Xe + (size_t)row * DIN + k0 + c4 * 4);
            ushort4 bv;
            bv.x = f2bf(xv.x); bv.y = f2bf(xv.y); bv.z = f2bf(xv.z); bv.w = f2bf(xv.w);
            *(ushort4*)&As[row * LDSS + c4 * 4] = bv;
        }
        // Stage B: 128x32 bf16 rows of Wt -> LDS [N][K]
#pragma unroll
        for (int i = 0; i < 2; i++) {
            int idx = tid + i * 256;        // 0..511
            int row = idx >> 2;             // 4 x 16B per row
            int c   = idx & 3;
            uint4 wv = *(const uint4*)(We + (size_t)row * DIN + k0 + c * 8);
            *(uint4*)&Bs[row * LDSS + c * 8] = wv;
        }
        __syncthreads();

        short8 af[4], bf[4];
#pragma unroll
        for (int i = 0; i < 4; i++)
            af[i] = *(const short8*)&As[(wm + i * 16 + lrow) * LDSS + quad * 8];
#pragma unroll
        for (int j = 0; j < 4; j++)
            bf[j] = *(const short8*)&Bs[(wn + j * 16 + lrow) * LDSS + quad * 8];
#pragma unroll
        for (int i = 0; i < 4; i++)
#pragma unroll
            for (int j = 0; j < 4; j++)
                acc[i][j] = __builtin_amdgcn_mfma_f32_16x16x32_bf16(af[i], bf[j], acc[i][j], 0, 0, 0);
        __syncthreads();
    }

    // Epilogue: bias + relu, fp32 store to H
    float bias[4];
#pragma unroll
    for (int j = 0; j < 4; j++)
        bias[j] = Bias[e * DOUT + n0 + wn + j * 16 + lrow];

    int tok0 = e * CAP + m0 + wm;
#pragma unroll
    for (int i = 0; i < 4; i++) {
#pragma unroll
        for (int j = 0; j < 4; j++) {
            int col = n0 + wn + j * 16 + lrow;
#pragma unroll
            for (int r = 0; r < 4; r++) {
                int row = tok0 + i * 16 + quad * 4 + r;
                float v = acc[i][j][r] + bias[j];
                v = fmaxf(v, 0.0f);
                H[(size_t)row * DOUT + col] = v;
            }
        }
    }
}

// ---- Kernel 3: in-place per-row LayerNorm on d_out ----
__global__ __launch_bounds__(256) void ln_kernel(float* __restrict__ H,
                                                 const float* __restrict__ G,
                                                 const float* __restrict__ Bt) {
    int row = blockIdx.x;           // 0..8191
    int e   = row >> 10;
    int tid  = threadIdx.x;
    int wave = tid >> 6;
    int lane = tid & 63;
    float* hp = H + (size_t)row * DOUT;

    float4 x = *(const float4*)(hp + tid * 4);
    float s  = x.x + x.y + x.z + x.w;
    float ss = fmaf(x.x, x.x, fmaf(x.y, x.y, fmaf(x.z, x.z, x.w * x.w)));

#pragma unroll
    for (int m = 32; m >= 1; m >>= 1) {
        s  += __shfl_xor(s, m);
        ss += __shfl_xor(ss, m);
    }
    __shared__ float red[8];
    if (lane == 0) { red[wave] = s; red[4 + wave] = ss; }
    __syncthreads();
    float ts  = red[0] + red[1] + red[2] + red[3];
    float tss = red[4] + red[5] + red[6] + red[7];

    float mean = ts * (1.0f / DOUT);
    float var  = tss * (1.0f / DOUT) - mean * mean;
    var = fmaxf(var, 0.0f);
    float rs = rsqrtf(var + LN_EPS);

    float4 g = *(const float4*)(G  + (size_t)e * DOUT + tid * 4);
    float4 b = *(const float4*)(Bt + (size_t)e * DOUT + tid * 4);
    float4 y;
    y.x = (x.x - mean) * rs * g.x + b.x;
    y.y = (x.y - mean) * rs * g.y + b.y;
    y.z = (x.z - mean) * rs * g.z + b.z;
    y.w = (x.w - mean) * rs * g.w + b.w;
    *(float4*)(hp + tid * 4) = y;
}

extern "C" void kernel_launch(void* const* d_in, const int* in_sizes, int n_in,
                              void* d_out, int out_size, void* d_ws, size_t ws_size,
                              hipStream_t stream) {
    const float* x  = (const float*)d_in[0];
    // d_in[1] = expert_frequency (int64) — equal loads, unused
    const float* W  = (const float*)d_in[2];
    const float* b  = (const float*)d_in[3];
    const float* g  = (const float*)d_in[4];
    const float* be = (const float*)d_in[5];
    unsigned short* Wt = (unsigned short*)d_ws;   // 8*1024*1024*2 = 16 MB
    float* out = (float*)d_out;

    dim3 tb(32, 8);
    dim3 tg(32, 32, 8);
    wt_kernel<<<tg, tb, 0, stream>>>(W, Wt);
    gemm_kernel<<<dim3(512), dim3(256), 0, stream>>>(x, Wt, b, out);
    ln_kernel<<<dim3(8192), dim3(256), 0, stream>>>(out, g, be);
}

// Round 2
// 152.970 us; speedup vs baseline: 1.0681x; 1.0681x over previous
//
#include <hip/hip_runtime.h>
#include <hip/hip_bf16.h>
#include <stdint.h>

#define T_TOK 8192
#define DIN   1024
#define DOUT  1024
#define NEXP  8
#define CAP   1024
#define LN_EPS 1e-5f

#define BM 128
#define BN 128
#define BK 32
#define LDSS 48   // fallback kernel only

typedef __attribute__((ext_vector_type(8))) short short8;
typedef __attribute__((ext_vector_type(4))) float f32x4;

__device__ __forceinline__ unsigned short f2bf(float f) {
    union { float f; unsigned int u; } v; v.f = f;
    unsigned int u = v.u;
    unsigned int r = u + 0x7FFFu + ((u >> 16) & 1u);   // RNE
    return (unsigned short)(r >> 16);
}

// async 16B global -> LDS (direct-to-shared DMA)
__device__ __forceinline__ void gld16(void* l, const void* g) {
    __builtin_amdgcn_global_load_lds(
        (const __attribute__((address_space(1))) unsigned int*)(uintptr_t)g,
        (__attribute__((address_space(3))) unsigned int*)(uintptr_t)l,
        16, 0, 0);
}

// ---- prep: X fp32 -> Xb bf16 (straight convert) ----
__global__ __launch_bounds__(256) void xb_kernel(const float* __restrict__ X,
                                                 unsigned short* __restrict__ Xb) {
    int i = blockIdx.x * 256 + threadIdx.x;     // 0 .. 2M-1 float4s
    float4 v = ((const float4*)X)[i];
    ushort4 o;
    o.x = f2bf(v.x); o.y = f2bf(v.y); o.z = f2bf(v.z); o.w = f2bf(v.w);
    ((ushort4*)Xb)[i] = o;
}

// ---- prep: W [E][K][N] fp32 -> Wt [E][N][K] bf16 (transpose + convert) ----
__global__ __launch_bounds__(256) void wt_kernel(const float* __restrict__ W,
                                                 unsigned short* __restrict__ Wt) {
    __shared__ float tile[32][33];
    int e  = blockIdx.z;
    int k0 = blockIdx.y * 32;
    int n0 = blockIdx.x * 32;
    const float* Wp = W + (size_t)e * DIN * DOUT;
    unsigned short* Wtp = Wt + (size_t)e * DIN * DOUT;
    int tid = threadIdx.x;
    {   // load 32k x 32n, float4-vectorized
        int k  = tid >> 3;          // 0..31
        int c4 = tid & 7;           // 0..7
        float4 v = *(const float4*)(Wp + (size_t)(k0 + k) * DOUT + n0 + c4 * 4);
        tile[k][c4 * 4 + 0] = v.x; tile[k][c4 * 4 + 1] = v.y;
        tile[k][c4 * 4 + 2] = v.z; tile[k][c4 * 4 + 3] = v.w;
    }
    __syncthreads();
    {   // write transposed, ushort4-vectorized
        int n  = tid >> 3;          // 0..31
        int kc = tid & 7;           // 0..7  (4 k's each)
        ushort4 o;
        o.x = f2bf(tile[kc * 4 + 0][n]);
        o.y = f2bf(tile[kc * 4 + 1][n]);
        o.z = f2bf(tile[kc * 4 + 2][n]);
        o.w = f2bf(tile[kc * 4 + 3][n]);
        *(ushort4*)(Wtp + (size_t)(n0 + n) * DIN + k0 + kc * 4) = o;
    }
}

// ---- main GEMM: h = relu(Xb_e * Wt_e^T + b_e), m97-style async staging ----
// 128x128x32 tile, 4 waves, 4x4 mfma_f32_16x16x32_bf16 each.
// Block swizzle: e = blk&7 so (round-robin WG->XCD) each XCD handles ONE
// expert: per-XCD working set = 2MB Wt + 2MB Xb -> fits 4MB L2.
__global__ __launch_bounds__(256) void gemm2_kernel(
    const unsigned short* __restrict__ Xb,   // [T][K] bf16
    const unsigned short* __restrict__ Wt,   // [E][N][K] bf16
    const float* __restrict__ Bias,
    float* __restrict__ H)
{
    __shared__ unsigned short As[BM * BK];   // 8 KB, rows of 64 B
    __shared__ unsigned short Bs[BN * BK];   // 8 KB

    int blk = blockIdx.x;                    // 0..511
    int e   = blk & 7;
    int m0  = (blk >> 6) * BM;               // 0..7 strips
    int n0  = ((blk >> 3) & 7) * BN;

    int tid  = threadIdx.x;
    int wave = tid >> 6;
    int lane = tid & 63;
    int wm   = (wave >> 1) * 64;
    int wn   = (wave & 1) * 64;
    int lrow = lane & 15;
    int quad = lane >> 4;

    const unsigned short* Ag = Xb + (size_t)(e * CAP + m0) * DIN;
    const unsigned short* Bg = Wt + (size_t)e * DOUT * DIN + (size_t)n0 * DIN;

    int l0 = tid;            // staging slots
    int l1 = tid + 256;
    int ar0 = l0 >> 2, ac0 = (l0 & 3) * 8;
    int ar1 = l1 >> 2, ac1 = (l1 & 3) * 8;

    f32x4 acc[4][4];
#pragma unroll
    for (int i = 0; i < 4; i++)
#pragma unroll
        for (int j = 0; j < 4; j++)
            acc[i][j] = (f32x4)(0.0f);

    for (int k0 = 0; k0 < DIN; k0 += BK) {
        gld16(&As[l0 * 8], Ag + (size_t)ar0 * DIN + k0 + ac0);
        gld16(&As[l1 * 8], Ag + (size_t)ar1 * DIN + k0 + ac1);
        gld16(&Bs[l0 * 8], Bg + (size_t)ar0 * DIN + k0 + ac0);
        gld16(&Bs[l1 * 8], Bg + (size_t)ar1 * DIN + k0 + ac1);
        __syncthreads();

        short8 af[4], bf[4];
#pragma unroll
        for (int i = 0; i < 4; i++)
            af[i] = *(const short8*)&As[(wm + i * 16 + lrow) * BK + quad * 8];
#pragma unroll
        for (int j = 0; j < 4; j++)
            bf[j] = *(const short8*)&Bs[(wn + j * 16 + lrow) * BK + quad * 8];
#pragma unroll
        for (int i = 0; i < 4; i++)
#pragma unroll
            for (int j = 0; j < 4; j++)
                acc[i][j] = __builtin_amdgcn_mfma_f32_16x16x32_bf16(af[i], bf[j], acc[i][j], 0, 0, 0);
        __syncthreads();
    }

    float bias[4];
#pragma unroll
    for (int j = 0; j < 4; j++)
        bias[j] = Bias[e * DOUT + n0 + wn + j * 16 + lrow];

    int tok0 = e * CAP + m0 + wm;
#pragma unroll
    for (int i = 0; i < 4; i++) {
#pragma unroll
        for (int j = 0; j < 4; j++) {
            int col = n0 + wn + j * 16 + lrow;
#pragma unroll
            for (int r = 0; r < 4; r++) {
                int row = tok0 + i * 16 + quad * 4 + r;
                float v = acc[i][j][r] + bias[j];
                H[(size_t)row * DOUT + col] = fmaxf(v, 0.0f);
            }
        }
    }
}

// ---- fallback GEMM (fp32 X staged in-kernel), used only if ws too small ----
__global__ __launch_bounds__(256, 2) void gemm_fb_kernel(
    const float* __restrict__ X,
    const unsigned short* __restrict__ Wt,
    const float* __restrict__ Bias,
    float* __restrict__ H)
{
    __shared__ unsigned short As[BM * LDSS];
    __shared__ unsigned short Bs[BN * LDSS];
    int blk = blockIdx.x;
    int e   = blk >> 6;
    int tt  = blk & 63;
    int m0  = (tt >> 3) * BM;
    int n0  = (tt & 7) * BN;
    int tid  = threadIdx.x;
    int wave = tid >> 6;
    int lane = tid & 63;
    int wm   = (wave >> 1) * 64;
    int wn   = (wave & 1) * 64;
    int lrow = lane & 15;
    int quad = lane >> 4;
    const float* Xe = X + (size_t)(e * CAP + m0) * DIN;
    const unsigned short* We = Wt + (size_t)e * DOUT * DIN + (size_t)n0 * DIN;
    f32x4 acc[4][4];
#pragma unroll
    for (int i = 0; i < 4; i++)
#pragma unroll
        for (int j = 0; j < 4; j++)
            acc[i][j] = (f32x4)(0.0f);
    for (int k0 = 0; k0 < DIN; k0 += BK) {
#pragma unroll
        for (int i = 0; i < 4; i++) {
            int idx = tid + i * 256;
            int row = idx >> 3;
            int c4  = idx & 7;
            const float4 xv = *(const float4*)(Xe + (size_t)row * DIN + k0 + c4 * 4);
            ushort4 bv;
            bv.x = f2bf(xv.x); bv.y = f2bf(xv.y); bv.z = f2bf(xv.z); bv.w = f2bf(xv.w);
            *(ushort4*)&As[row * LDSS + c4 * 4] = bv;
        }
#pragma unroll
        for (int i = 0; i < 2; i++) {
            int idx = tid + i * 256;
            int row = idx >> 2;
            int c   = idx & 3;
            uint4 wv = *(const uint4*)(We + (size_t)row * DIN + k0 + c * 8);
            *(uint4*)&Bs[row * LDSS + c * 8] = wv;
        }
        __syncthreads();
        short8 af[4], bf[4];
#pragma unroll
        for (int i = 0; i < 4; i++)
            af[i] = *(const short8*)&As[(wm + i * 16 + lrow) * LDSS + quad * 8];
#pragma unroll
        for (int j = 0; j < 4; j++)
            bf[j] = *(const short8*)&Bs[(wn + j * 16 + lrow) * LDSS + quad * 8];
#pragma unroll
        for (int i = 0; i < 4; i++)
#pragma unroll
            for (int j = 0; j < 4; j++)
                acc[i][j] = __builtin_amdgcn_mfma_f32_16x16x32_bf16(af[i], bf[j], acc[i][j], 0, 0, 0);
        __syncthreads();
    }
    float bias[4];
#pragma unroll
    for (int j = 0; j < 4; j++)
        bias[j] = Bias[e * DOUT + n0 + wn + j * 16 + lrow];
    int tok0 = e * CAP + m0 + wm;
#pragma unroll
    for (int i = 0; i < 4; i++)
#pragma unroll
        for (int j = 0; j < 4; j++) {
            int col = n0 + wn + j * 16 + lrow;
#pragma unroll
            for (int r = 0; r < 4; r++) {
                int row = tok0 + i * 16 + quad * 4 + r;
                float v = acc[i][j][r] + bias[j];
                H[(size_t)row * DOUT + col] = fmaxf(v, 0.0f);
            }
        }
}

// ---- in-place per-row LayerNorm ----
__global__ __launch_bounds__(256) void ln_kernel(float* __restrict__ H,
                                                 const float* __restrict__ G,
                                                 const float* __restrict__ Bt) {
    int row = blockIdx.x;
    int e   = row >> 10;
    int tid  = threadIdx.x;
    int wave = tid >> 6;
    int lane = tid & 63;
    float* hp = H + (size_t)row * DOUT;

    float4 x = *(const float4*)(hp + tid * 4);
    float s  = x.x + x.y + x.z + x.w;
    float ss = fmaf(x.x, x.x, fmaf(x.y, x.y, fmaf(x.z, x.z, x.w * x.w)));
#pragma unroll
    for (int m = 32; m >= 1; m >>= 1) {
        s  += __shfl_xor(s, m);
        ss += __shfl_xor(ss, m);
    }
    __shared__ float red[8];
    if (lane == 0) { red[wave] = s; red[4 + wave] = ss; }
    __syncthreads();
    float ts  = red[0] + red[1] + red[2] + red[3];
    float tss = red[4] + red[5] + red[6] + red[7];
    float mean = ts * (1.0f / DOUT);
    float var  = fmaxf(tss * (1.0f / DOUT) - mean * mean, 0.0f);
    float rs = rsqrtf(var + LN_EPS);
    float4 g = *(const float4*)(G  + (size_t)e * DOUT + tid * 4);
    float4 b = *(const float4*)(Bt + (size_t)e * DOUT + tid * 4);
    float4 y;
    y.x = (x.x - mean) * rs * g.x + b.x;
    y.y = (x.y - mean) * rs * g.y + b.y;
    y.z = (x.z - mean) * rs * g.z + b.z;
    y.w = (x.w - mean) * rs * g.w + b.w;
    *(float4*)(hp + tid * 4) = y;
}

extern "C" void kernel_launch(void* const* d_in, const int* in_sizes, int n_in,
                              void* d_out, int out_size, void* d_ws, size_t ws_size,
                              hipStream_t stream) {
    const float* x  = (const float*)d_in[0];
    const float* W  = (const float*)d_in[2];
    const float* b  = (const float*)d_in[3];
    const float* g  = (const float*)d_in[4];
    const float* be = (const float*)d_in[5];
    float* out = (float*)d_out;

    unsigned short* Wt = (unsigned short*)d_ws;                    // 16 MB
    const size_t WT_BYTES = (size_t)NEXP * DIN * DOUT * 2;
    const size_t XB_BYTES = (size_t)T_TOK * DIN * 2;

    dim3 tb(256);
    wt_kernel<<<dim3(32, 32, 8), tb, 0, stream>>>(W, Wt);

    if (ws_size >= WT_BYTES + XB_BYTES) {
        unsigned short* Xb = (unsigned short*)((char*)d_ws + WT_BYTES);  // +16 MB
        xb_kernel<<<dim3(8192), tb, 0, stream>>>(x, Xb);
        gemm2_kernel<<<dim3(512), tb, 0, stream>>>(Xb, Wt, b, out);
    } else {
        gemm_fb_kernel<<<dim3(512), tb, 0, stream>>>(x, Wt, b, out);
    }
    ln_kernel<<<dim3(8192), tb, 0, stream>>>(out, g, be);
}